// Round 4
// baseline (514.071 us; speedup 1.0000x reference)
//
#include <hip/hip_runtime.h>

// LBP 'var' texture loss, MI355X. Shapes fixed by reference: [16,3,512,512] f32.
// A (output) and B (target) run the identical 52-tap stencil -> interleave as
// float2 {A,B} and use packed fp32 (v_pk_fma_f32). Round-4 changes:
//  - __launch_bounds__(256,4): VGPR cap 128 so the 5x8 f2 window (80 VGPR)
//    stays register-resident (round 3: VGPR=36 -> LDS re-reads, VALUBusy 62%)
//  - fused finalize: last block reduces the per-block partials (no 2nd kernel)

typedef float f2 __attribute__((ext_vector_type(2)));

#define IMG_H 512
#define IMG_W 512
#define TILE_X 64
#define TILE_Y 16
#define LDS_H  20   // TILE_Y + 2*2 halo rows
#define LDS_CP 72   // pair-cols covered per row: [bx*64-4, bx*64+68)
#define LDS_SP 74   // padded pair stride (592 B, 16B multiple)

// Circle offsets, exactly matching np.round(±2*sin/cos(2*pi*i/16), 8)
constexpr double RPV[16] = {
   0.0,        -0.76536686, -1.41421356, -1.84775907,
  -2.0,        -1.84775907, -1.41421356, -0.76536686,
   0.0,         0.76536686,  1.41421356,  1.84775907,
   2.0,         1.84775907,  1.41421356,  0.76536686
};
constexpr double CPV[16] = {
   2.0,         1.84775907,  1.41421356,  0.76536686,
   0.0,        -0.76536686, -1.41421356, -1.84775907,
  -2.0,        -1.84775907, -1.41421356, -0.76536686,
   0.0,         0.76536686,  1.41421356,  1.84775907
};

constexpr int cfloor(double x) {
  int i = (int)x;
  return (x < (double)i) ? i - 1 : i;
}

__device__ __forceinline__ f2 splat(float x) { f2 r; r.x = x; r.y = x; return r; }

// One circle point, packed over {A,B}. Tap order 00,01,10,11 with w<=1e-12
// skipped, mirroring the reference loop exactly (absmax 0.0 in r2/r3 -> keep).
template<int I>
__device__ __forceinline__ void lbp_point(const f2 (&w)[5][8], int px,
                                          f2& s1, f2& s2) {
  constexpr double rp = RPV[I], cp = CPV[I];
  constexpr int fr = cfloor(rp), fc = cfloor(cp);
  constexpr double tr = rp - (double)fr, tc = cp - (double)fc;
  constexpr double W00 = (1.0 - tr) * (1.0 - tc);
  constexpr double W01 = (1.0 - tr) * tc;
  constexpr double W10 = tr * (1.0 - tc);
  constexpr double W11 = tr * tc;
  f2 v = splat(0.0f);
  if constexpr (W00 > 1e-12)
    v = __builtin_elementwise_fma(splat((float)W00), w[fr + 2][px + fc + 2], v);
  if constexpr (W01 > 1e-12)
    v = __builtin_elementwise_fma(splat((float)W01), w[fr + 2][px + fc + 3], v);
  if constexpr (W10 > 1e-12)
    v = __builtin_elementwise_fma(splat((float)W10), w[fr + 3][px + fc + 2], v);
  if constexpr (W11 > 1e-12)
    v = __builtin_elementwise_fma(splat((float)W11), w[fr + 3][px + fc + 3], v);
  s1 = s1 + v;
  s2 = __builtin_elementwise_fma(v, v, s2);
}

__device__ __forceinline__ void lbp_all16(const f2 (&w)[5][8], int px,
                                          f2& s1, f2& s2) {
  lbp_point<0>(w, px, s1, s2);  lbp_point<1>(w, px, s1, s2);
  lbp_point<2>(w, px, s1, s2);  lbp_point<3>(w, px, s1, s2);
  lbp_point<4>(w, px, s1, s2);  lbp_point<5>(w, px, s1, s2);
  lbp_point<6>(w, px, s1, s2);  lbp_point<7>(w, px, s1, s2);
  lbp_point<8>(w, px, s1, s2);  lbp_point<9>(w, px, s1, s2);
  lbp_point<10>(w, px, s1, s2); lbp_point<11>(w, px, s1, s2);
  lbp_point<12>(w, px, s1, s2); lbp_point<13>(w, px, s1, s2);
  lbp_point<14>(w, px, s1, s2); lbp_point<15>(w, px, s1, s2);
}

__global__ __launch_bounds__(256, 4)  // min 4 waves/EU -> VGPR cap 128: window stays in regs
void lbp_loss_kernel(const float* __restrict__ A, const float* __restrict__ B,
                     double* __restrict__ part, unsigned int* __restrict__ counter,
                     float* __restrict__ out, int nblocks, double inv_n) {
  __shared__ __align__(16) f2 tile[LDS_H][LDS_SP];
  __shared__ double bsum[4];
  __shared__ int lastFlag;

  const int tid = threadIdx.x;
  const int bx = blockIdx.x, by = blockIdx.y, z = blockIdx.z;
  const int row0 = by * TILE_Y - 2;
  const int col0 = bx * TILE_X - 4;   // aligned-float4 halo start
  const size_t ibase = (size_t)z * (IMG_H * IMG_W);

  // Stage interleaved {A,B} pairs: 18 aligned float4-quads per row x 20 rows.
  // A quad is fully inside [0,512) or fully outside -> single bounds check.
  const int QUADS = LDS_CP / 4;            // 18
  const int SLOTS = LDS_H * QUADS;         // 360 -> 2 iterations
  for (int idx = tid; idx < SLOTS; idx += 256) {
    const int r = idx / QUADS;
    const int q = idx - r * QUADS;
    const int gr = row0 + r;
    const int gc = col0 + q * 4;
    float4 a = make_float4(0.f, 0.f, 0.f, 0.f);
    float4 b = make_float4(0.f, 0.f, 0.f, 0.f);
    if ((unsigned)gr < (unsigned)IMG_H && (unsigned)gc < (unsigned)IMG_W) {
      const size_t off = ibase + (size_t)gr * IMG_W + gc;
      a = *(const float4*)&A[off];
      b = *(const float4*)&B[off];
    }
    f2* dst = &tile[r][q * 4];
    dst[0] = f2{a.x, b.x};
    dst[1] = f2{a.y, b.y};
    dst[2] = f2{a.z, b.z};
    dst[3] = f2{a.w, b.w};
  }
  __syncthreads();

  const int tx = tid & 15;   // 16 threads across, 4 px each -> 64 cols
  const int ty = tid >> 4;   // 16 rows

  // 5x8 pair window, rows ty..ty+4, pair-cols tx*4+2..tx*4+9.
  // Byte offset (74r + 4tx + 2)*8 = 16B aligned -> 4x ds_read_b128 per row.
  f2 w[5][8];
  #pragma unroll
  for (int r = 0; r < 5; ++r) {
    const f2* lp = &tile[ty + r][tx * 4 + 2];
    *(float4*)&w[r][0] = *(const float4*)(lp + 0);
    *(float4*)&w[r][2] = *(const float4*)(lp + 2);
    *(float4*)&w[r][4] = *(const float4*)(lp + 4);
    *(float4*)&w[r][6] = *(const float4*)(lp + 6);
  }

  float local = 0.0f;
  #pragma unroll
  for (int px = 0; px < 4; ++px) {
    f2 s1 = splat(0.0f), s2 = splat(0.0f);
    lbp_all16(w, px, s1, s2);
    f2 mean = s1 * 0.0625f;
    f2 var  = __builtin_elementwise_fma(-mean, mean, s2 * 0.0625f);
    const float d = var.x - var.y;
    local = fmaf(d, d, local);
  }

  // wave64 shuffle reduce -> 4 wave sums -> one f64 partial per block.
  #pragma unroll
  for (int off = 32; off > 0; off >>= 1)
    local += __shfl_down(local, off, 64);
  if ((tid & 63) == 0) bsum[tid >> 6] = (double)local;
  __syncthreads();

  if (tid == 0) {
    const int bflat = bx + gridDim.x * (by + gridDim.y * z);
    const double psum = bsum[0] + bsum[1] + bsum[2] + bsum[3];
    // device-scope release store, then count this block as done
    __hip_atomic_store(&part[bflat], psum, __ATOMIC_RELEASE,
                       __HIP_MEMORY_SCOPE_AGENT);
    unsigned int old = __hip_atomic_fetch_add(counter, 1u, __ATOMIC_ACQ_REL,
                                              __HIP_MEMORY_SCOPE_AGENT);
    lastFlag = (old == (unsigned)(nblocks - 1));
  }
  __syncthreads();

  // Last block to finish sums all partials (12288 f64, L2-resident by now).
  if (lastFlag) {
    double s = 0.0;
    for (int i = tid; i < nblocks; i += 256)   // 48 iterations
      s += __hip_atomic_load(&part[i], __ATOMIC_RELAXED, __HIP_MEMORY_SCOPE_AGENT);
    #pragma unroll
    for (int off = 32; off > 0; off >>= 1)
      s += __shfl_down(s, off, 64);
    __syncthreads();                 // bsum reuse
    if ((tid & 63) == 0) bsum[tid >> 6] = s;
    __syncthreads();
    if (tid == 0)
      out[0] = (float)((bsum[0] + bsum[1] + bsum[2] + bsum[3]) * inv_n);
  }
}

extern "C" void kernel_launch(void* const* d_in, const int* in_sizes, int n_in,
                              void* d_out, int out_size, void* d_ws, size_t ws_size,
                              hipStream_t stream) {
  const float* A = (const float*)d_in[0];   // output
  const float* B = (const float*)d_in[1];   // target
  float* out = (float*)d_out;
  // d_ws layout: [0..3] u32 counter (zeroed), [16..] 12288 f64 partials
  unsigned int* counter = (unsigned int*)d_ws;
  double* part = (double*)((char*)d_ws + 16);

  hipMemsetAsync(d_ws, 0, 16, stream);      // counter <- 0 (ws is 0xAA-poisoned)

  const int total = in_sizes[0];                 // 16*3*512*512 = 12,582,912
  const int BC = total / (IMG_H * IMG_W);        // 48
  dim3 grid(IMG_W / TILE_X, IMG_H / TILE_Y, BC); // (8, 32, 48)
  const int nblocks = grid.x * grid.y * grid.z;  // 12288
  lbp_loss_kernel<<<grid, 256, 0, stream>>>(A, B, part, counter, out, nblocks,
                                            1.0 / (double)total);
}

// Round 7
// 388.140 us; speedup vs baseline: 1.3244x; 1.3244x over previous
//
#include <hip/hip_runtime.h>

// LBP 'var' texture loss, MI355X. [16,3,512,512] f32.
// A/B run the identical 52-tap stencil -> packed fp32 over {A,B} pairs.
// r5/r6/r7: (1) RELAXED device-scope atomicAdd fused finalize (r4's agent-scope
//     release/acquire emitted per-block L2 wb/inv -> 10x regression; r2 proved
//     49k relaxed adds cost ~0). Ordering: consume the returned old value to
//     force vmcnt(0) before the counter bump; last block reads acc via RMW.
//     (2) asm-pin the 5x8 f2 window into 80 VGPRs (r3: VGPR=36 -> compiler
//     re-read LDS per tap, VALUBusy 62% with 38% lgkm-idle).

typedef float f2 __attribute__((ext_vector_type(2)));
typedef float f4 __attribute__((ext_vector_type(4)));

#define IMG_H 512
#define IMG_W 512
#define TILE_X 64
#define TILE_Y 16
#define LDS_H  20   // TILE_Y + 4 halo rows
#define LDS_CP 72   // pair-cols per row: [bx*64-4, bx*64+68)
#define LDS_SP 74   // padded pair stride (592 B = 37*16 -> b128-aligned)

// Circle offsets, exactly matching np.round(±2*sin/cos(2*pi*i/16), 8)
constexpr double RPV[16] = {
   0.0,        -0.76536686, -1.41421356, -1.84775907,
  -2.0,        -1.84775907, -1.41421356, -0.76536686,
   0.0,         0.76536686,  1.41421356,  1.84775907,
   2.0,         1.84775907,  1.41421356,  0.76536686
};
constexpr double CPV[16] = {
   2.0,         1.84775907,  1.41421356,  0.76536686,
   0.0,        -0.76536686, -1.41421356, -1.84775907,
  -2.0,        -1.84775907, -1.41421356, -0.76536686,
   0.0,         0.76536686,  1.41421356,  1.84775907
};

constexpr int cfloor(double x) {
  int i = (int)x;
  return (x < (double)i) ? i - 1 : i;
}

__device__ __forceinline__ f2 splat(float x) { f2 r; r.x = x; r.y = x; return r; }

// One circle point, packed over {A,B}. w = f2 view of the 5x8 window
// (row stride 8). Tap order 00,01,10,11, w<=1e-12 skipped, exactly as ref.
template<int I>
__device__ __forceinline__ void lbp_point(const f2* w, int px, f2& s1, f2& s2) {
  constexpr double rp = RPV[I], cp = CPV[I];
  constexpr int fr = cfloor(rp), fc = cfloor(cp);
  constexpr double tr = rp - (double)fr, tc = cp - (double)fc;
  constexpr double W00 = (1.0 - tr) * (1.0 - tc);
  constexpr double W01 = (1.0 - tr) * tc;
  constexpr double W10 = tr * (1.0 - tc);
  constexpr double W11 = tr * tc;
  f2 v = splat(0.0f);
  if constexpr (W00 > 1e-12)
    v = __builtin_elementwise_fma(splat((float)W00), w[(fr + 2) * 8 + px + fc + 2], v);
  if constexpr (W01 > 1e-12)
    v = __builtin_elementwise_fma(splat((float)W01), w[(fr + 2) * 8 + px + fc + 3], v);
  if constexpr (W10 > 1e-12)
    v = __builtin_elementwise_fma(splat((float)W10), w[(fr + 3) * 8 + px + fc + 2], v);
  if constexpr (W11 > 1e-12)
    v = __builtin_elementwise_fma(splat((float)W11), w[(fr + 3) * 8 + px + fc + 3], v);
  s1 = s1 + v;
  s2 = __builtin_elementwise_fma(v, v, s2);
}

__device__ __forceinline__ void lbp_all16(const f2* w, int px, f2& s1, f2& s2) {
  lbp_point<0>(w, px, s1, s2);  lbp_point<1>(w, px, s1, s2);
  lbp_point<2>(w, px, s1, s2);  lbp_point<3>(w, px, s1, s2);
  lbp_point<4>(w, px, s1, s2);  lbp_point<5>(w, px, s1, s2);
  lbp_point<6>(w, px, s1, s2);  lbp_point<7>(w, px, s1, s2);
  lbp_point<8>(w, px, s1, s2);  lbp_point<9>(w, px, s1, s2);
  lbp_point<10>(w, px, s1, s2); lbp_point<11>(w, px, s1, s2);
  lbp_point<12>(w, px, s1, s2); lbp_point<13>(w, px, s1, s2);
  lbp_point<14>(w, px, s1, s2); lbp_point<15>(w, px, s1, s2);
}

__global__ __launch_bounds__(256, 4)  // VGPR cap 128: window + accums fit, no spill
void lbp_loss_kernel(const float* __restrict__ A, const float* __restrict__ B,
                     double* acc, unsigned int* counter,
                     float* __restrict__ out, int nblocks, double inv_n) {
  __shared__ __align__(16) f2 tile[LDS_H][LDS_SP];
  __shared__ double bsum[4];

  const int tid = threadIdx.x;
  const int bx = blockIdx.x, by = blockIdx.y, z = blockIdx.z;
  const int row0 = by * TILE_Y - 2;
  const int col0 = bx * TILE_X - 4;   // aligned-float4 halo start
  const size_t ibase = (size_t)z * (IMG_H * IMG_W);

  // Stage interleaved {A,B} pairs: 18 aligned float4-quads per row x 20 rows.
  // A quad is fully inside [0,512) or fully outside -> single bounds check.
  const int QUADS = LDS_CP / 4;            // 18
  const int SLOTS = LDS_H * QUADS;         // 360 -> 2 iterations
  for (int idx = tid; idx < SLOTS; idx += 256) {
    const int r = idx / QUADS;
    const int q = idx - r * QUADS;
    const int gr = row0 + r;
    const int gc = col0 + q * 4;
    f4 a = {0.f, 0.f, 0.f, 0.f};
    f4 b = {0.f, 0.f, 0.f, 0.f};
    if ((unsigned)gr < (unsigned)IMG_H && (unsigned)gc < (unsigned)IMG_W) {
      const size_t off = ibase + (size_t)gr * IMG_W + gc;
      a = *(const f4*)&A[off];
      b = *(const f4*)&B[off];
    }
    f2* dst = &tile[r][q * 4];
    dst[0] = f2{a.x, b.x};
    dst[1] = f2{a.y, b.y};
    dst[2] = f2{a.z, b.z};
    dst[3] = f2{a.w, b.w};
  }
  __syncthreads();

  const int tx = tid & 15;   // 16 threads across, 4 px each -> 64 cols
  const int ty = tid >> 4;   // 16 rows

  // 5x8 f2 window, rows ty..ty+4, pair-cols tx*4+2..tx*4+9.
  // Byte offset (74r + 4tx + 2)*8 is 16B-aligned -> 4x ds_read_b128 per row.
  f4 wq[5][4];
  #pragma unroll
  for (int r = 0; r < 5; ++r) {
    const f4* lp = (const f4*)&tile[ty + r][tx * 4 + 2];
    wq[r][0] = lp[0]; wq[r][1] = lp[1]; wq[r][2] = lp[2]; wq[r][3] = lp[3];
  }
  // Pin the window into 80 VGPRs: compiler must materialize all 20 b128 loads
  // here and may not re-read LDS during the compute (r3 failure mode).
  #pragma unroll
  for (int r = 0; r < 5; ++r) {
    #pragma unroll
    for (int q = 0; q < 4; ++q)
      asm volatile("" : "+v"(wq[r][q]));
  }

  const f2* w = (const f2*)&wq[0][0];

  float local = 0.0f;
  #pragma unroll
  for (int px = 0; px < 4; ++px) {
    f2 s1 = splat(0.0f), s2 = splat(0.0f);
    lbp_all16(w, px, s1, s2);
    f2 mean = s1 * 0.0625f;
    f2 var  = __builtin_elementwise_fma(-mean, mean, s2 * 0.0625f);
    const float d = var.x - var.y;
    local = fmaf(d, d, local);
  }

  // wave64 shuffle reduce -> 4 wave sums -> one f64 add per block.
  #pragma unroll
  for (int off = 32; off > 0; off >>= 1)
    local += __shfl_down(local, off, 64);
  if ((tid & 63) == 0) bsum[tid >> 6] = (double)local;
  __syncthreads();

  if (tid == 0) {
    const double psum = bsum[0] + bsum[1] + bsum[2] + bsum[3];
    // RELAXED device-scope f64 atomic (no cache maintenance; r2-proven cheap).
    const double old = atomicAdd(acc, psum);
    // Consume the returned value: forces s_waitcnt vmcnt(0) -> our add has
    // performed at the coherence point before the counter bump below issues.
    asm volatile("" : : "v"(old) : "memory");
    const unsigned prev = atomicAdd(counter, 1u);
    if (prev == (unsigned)(nblocks - 1)) {
      // All blocks' acc-adds performed (each ordered before its counter bump,
      // RMWs to one address are totally ordered). Read via RMW.
      const double tot = atomicAdd(acc, 0.0);
      out[0] = (float)(tot * inv_n);
    }
  }
}

extern "C" void kernel_launch(void* const* d_in, const int* in_sizes, int n_in,
                              void* d_out, int out_size, void* d_ws, size_t ws_size,
                              hipStream_t stream) {
  const float* A = (const float*)d_in[0];   // output
  const float* B = (const float*)d_in[1];   // target
  float* out = (float*)d_out;
  // d_ws: [0,8) f64 accumulator, [8,12) u32 counter -- both zeroed per launch
  double* acc = (double*)d_ws;
  unsigned int* counter = (unsigned int*)((char*)d_ws + 8);

  hipMemsetAsync(d_ws, 0, 16, stream);

  const int total = in_sizes[0];                 // 16*3*512*512 = 12,582,912
  const int BC = total / (IMG_H * IMG_W);        // 48
  dim3 grid(IMG_W / TILE_X, IMG_H / TILE_Y, BC); // (8, 32, 48)
  const int nblocks = grid.x * grid.y * grid.z;  // 12288
  lbp_loss_kernel<<<grid, 256, 0, stream>>>(A, B, acc, counter, out, nblocks,
                                            1.0 / (double)total);
}

// Round 12
// 179.698 us; speedup vs baseline: 2.8608x; 2.1600x over previous
//
#include <hip/hip_runtime.h>

// LBP 'var' texture loss, MI355X. [16,3,512,512] f32.
// A/B run the identical 52-tap stencil -> packed fp32 over {A,B} pairs
// (v_pk_fma_f32; r2->r3 halved VALU cycles exactly as predicted).
// r8..r12: - REVERT r5/r7's return-value atomic ordering (same-address f64
//       RMW with consumed return serializes block retirement at ~24ns/atomic
//       -> 296us). Fire-and-forget atomicAdd only (r2: 49k adds ~ free).
//     - REVERT asm window pin + launch_bounds min-waves (failed: VGPR 48,
//       window still not resident; confounded r7).
//     - TILE_Y 16->32 @ 512 threads: halo 36/32 rows vs 20/16 (-10% staging
//       work), half the blocks (-50% per-block barrier/reduce/atomic cost).

typedef float f2 __attribute__((ext_vector_type(2)));
typedef float f4 __attribute__((ext_vector_type(4)));

#define IMG_H 512
#define IMG_W 512
#define TILE_X 64
#define TILE_Y 32
#define LDS_H  36   // TILE_Y + 4 halo rows
#define LDS_CP 72   // pair-cols per row: [bx*64-4, bx*64+68)
#define LDS_SP 74   // padded pair stride (592 B = 37*16 -> b128-aligned)

// Circle offsets, exactly matching np.round(±2*sin/cos(2*pi*i/16), 8)
constexpr double RPV[16] = {
   0.0,        -0.76536686, -1.41421356, -1.84775907,
  -2.0,        -1.84775907, -1.41421356, -0.76536686,
   0.0,         0.76536686,  1.41421356,  1.84775907,
   2.0,         1.84775907,  1.41421356,  0.76536686
};
constexpr double CPV[16] = {
   2.0,         1.84775907,  1.41421356,  0.76536686,
   0.0,        -0.76536686, -1.41421356, -1.84775907,
  -2.0,        -1.84775907, -1.41421356, -0.76536686,
   0.0,         0.76536686,  1.41421356,  1.84775907
};

constexpr int cfloor(double x) {
  int i = (int)x;
  return (x < (double)i) ? i - 1 : i;
}

__device__ __forceinline__ f2 splat(float x) { f2 r; r.x = x; r.y = x; return r; }

// One circle point, packed over {A,B}. Window w: 5 rows x 8 f2, row stride 8.
// Tap order 00,01,10,11, w<=1e-12 skipped, exactly as the reference.
template<int I>
__device__ __forceinline__ void lbp_point(const f2 (&w)[5][8], int px,
                                          f2& s1, f2& s2) {
  constexpr double rp = RPV[I], cp = CPV[I];
  constexpr int fr = cfloor(rp), fc = cfloor(cp);
  constexpr double tr = rp - (double)fr, tc = cp - (double)fc;
  constexpr double W00 = (1.0 - tr) * (1.0 - tc);
  constexpr double W01 = (1.0 - tr) * tc;
  constexpr double W10 = tr * (1.0 - tc);
  constexpr double W11 = tr * tc;
  f2 v = splat(0.0f);
  if constexpr (W00 > 1e-12)
    v = __builtin_elementwise_fma(splat((float)W00), w[fr + 2][px + fc + 2], v);
  if constexpr (W01 > 1e-12)
    v = __builtin_elementwise_fma(splat((float)W01), w[fr + 2][px + fc + 3], v);
  if constexpr (W10 > 1e-12)
    v = __builtin_elementwise_fma(splat((float)W10), w[fr + 3][px + fc + 2], v);
  if constexpr (W11 > 1e-12)
    v = __builtin_elementwise_fma(splat((float)W11), w[fr + 3][px + fc + 3], v);
  s1 = s1 + v;
  s2 = __builtin_elementwise_fma(v, v, s2);
}

__device__ __forceinline__ void lbp_all16(const f2 (&w)[5][8], int px,
                                          f2& s1, f2& s2) {
  lbp_point<0>(w, px, s1, s2);  lbp_point<1>(w, px, s1, s2);
  lbp_point<2>(w, px, s1, s2);  lbp_point<3>(w, px, s1, s2);
  lbp_point<4>(w, px, s1, s2);  lbp_point<5>(w, px, s1, s2);
  lbp_point<6>(w, px, s1, s2);  lbp_point<7>(w, px, s1, s2);
  lbp_point<8>(w, px, s1, s2);  lbp_point<9>(w, px, s1, s2);
  lbp_point<10>(w, px, s1, s2); lbp_point<11>(w, px, s1, s2);
  lbp_point<12>(w, px, s1, s2); lbp_point<13>(w, px, s1, s2);
  lbp_point<14>(w, px, s1, s2); lbp_point<15>(w, px, s1, s2);
}

__global__ __launch_bounds__(512)
void lbp_loss_kernel(const float* __restrict__ A, const float* __restrict__ B,
                     double* acc) {
  __shared__ __align__(16) f2 tile[LDS_H][LDS_SP];
  __shared__ double bsum[8];

  const int tid = threadIdx.x;
  const int bx = blockIdx.x, by = blockIdx.y, z = blockIdx.z;
  const int row0 = by * TILE_Y - 2;
  const int col0 = bx * TILE_X - 4;   // aligned-float4 halo start
  const size_t ibase = (size_t)z * (IMG_H * IMG_W);

  // Stage interleaved {A,B} pairs: 18 aligned float4-quads per row x 36 rows.
  // A quad is fully inside [0,512) or fully outside -> single bounds check.
  const int QUADS = LDS_CP / 4;            // 18
  const int SLOTS = LDS_H * QUADS;         // 648 -> 2 iterations at 512 thr
  for (int idx = tid; idx < SLOTS; idx += 512) {
    const int r = idx / QUADS;
    const int q = idx - r * QUADS;
    const int gr = row0 + r;
    const int gc = col0 + q * 4;
    f4 a = {0.f, 0.f, 0.f, 0.f};
    f4 b = {0.f, 0.f, 0.f, 0.f};
    if ((unsigned)gr < (unsigned)IMG_H && (unsigned)gc < (unsigned)IMG_W) {
      const size_t off = ibase + (size_t)gr * IMG_W + gc;
      a = *(const f4*)&A[off];
      b = *(const f4*)&B[off];
    }
    f2* dst = &tile[r][q * 4];
    dst[0] = f2{a.x, b.x};
    dst[1] = f2{a.y, b.y};
    dst[2] = f2{a.z, b.z};
    dst[3] = f2{a.w, b.w};
  }
  __syncthreads();

  const int tx = tid & 15;   // 16 threads across, 4 px each -> 64 cols
  const int ty = tid >> 4;   // 32 rows

  // 5x8 f2 window, rows ty..ty+4, pair-cols tx*4+2..tx*4+9.
  // Byte offset (74r + 4tx + 2)*8 is 16B-aligned -> 4x ds_read_b128 per row.
  f2 w[5][8];
  #pragma unroll
  for (int r = 0; r < 5; ++r) {
    const f4* lp = (const f4*)&tile[ty + r][tx * 4 + 2];
    *(f4*)&w[r][0] = lp[0];
    *(f4*)&w[r][2] = lp[1];
    *(f4*)&w[r][4] = lp[2];
    *(f4*)&w[r][6] = lp[3];
  }

  float local = 0.0f;
  #pragma unroll
  for (int px = 0; px < 4; ++px) {
    f2 s1 = splat(0.0f), s2 = splat(0.0f);
    lbp_all16(w, px, s1, s2);
    f2 mean = s1 * 0.0625f;
    f2 var  = __builtin_elementwise_fma(-mean, mean, s2 * 0.0625f);
    const float d = var.x - var.y;
    local = fmaf(d, d, local);
  }

  // wave64 shuffle reduce -> 8 wave sums -> ONE fire-and-forget f64 atomic
  // per block (r2-proven ~free; r7 proved waiting on its return is fatal).
  #pragma unroll
  for (int off = 32; off > 0; off >>= 1)
    local += __shfl_down(local, off, 64);
  if ((tid & 63) == 0) bsum[tid >> 6] = (double)local;
  __syncthreads();
  if (tid == 0) {
    double psum = 0.0;
    #pragma unroll
    for (int i = 0; i < 8; ++i) psum += bsum[i];
    atomicAdd(acc, psum);   // return value intentionally unused
  }
}

__global__ void finalize_kernel(const double* __restrict__ acc,
                                float* __restrict__ out, double inv_n) {
  out[0] = (float)(acc[0] * inv_n);
}

extern "C" void kernel_launch(void* const* d_in, const int* in_sizes, int n_in,
                              void* d_out, int out_size, void* d_ws, size_t ws_size,
                              hipStream_t stream) {
  const float* A = (const float*)d_in[0];   // output
  const float* B = (const float*)d_in[1];   // target
  float* out = (float*)d_out;
  double* acc = (double*)d_ws;              // single f64 accumulator

  hipMemsetAsync(acc, 0, sizeof(double), stream);

  const int total = in_sizes[0];                 // 16*3*512*512 = 12,582,912
  const int BC = total / (IMG_H * IMG_W);        // 48
  dim3 grid(IMG_W / TILE_X, IMG_H / TILE_Y, BC); // (8, 16, 48) = 6144 blocks
  lbp_loss_kernel<<<grid, 512, 0, stream>>>(A, B, acc);
  finalize_kernel<<<1, 1, 0, stream>>>(acc, out, 1.0 / (double)total);
}